// Round 4
// baseline (1058.684 us; speedup 1.0000x reference)
//
#include <hip/hip_runtime.h>

#define NN   50000
#define EE   800000
#define ET   850000          // EE + NN self loops
#define INC  128
#define HID  256
#define OUTC 64
#define NEG  0.2f
#define BNEPS 1e-5f

static __device__ __forceinline__ float b2f(unsigned short u) {
    return __uint_as_float(((unsigned)u) << 16);
}
static __device__ __forceinline__ unsigned short f2b(float f) {
    unsigned u = __float_as_uint(f);
    unsigned r = u + 0x7FFFu + ((u >> 16) & 1u);
    return (unsigned short)(r >> 16);
}
static __device__ __forceinline__ float leaky(float x) {
    return x > 0.f ? x : NEG * x;
}

// ---------------- dtype detection ----------------
// Edge width: if int64 (LE), odd 32-bit words of row 0 are high words == 0.
__global__ void k_detect_w(const int* __restrict__ ei, int* __restrict__ flagW) {
    int i = blockIdx.x * 256 + threadIdx.x;
    if (i < 65536 && ei[2 * i + 1] != 0) atomicOr(flagW, 1);
}

// Float width: sample 4096 words of x (normal(0,1) data).
// bf16-packed: byte1 = sign+exp[7:1] of a bf16 normal -> (byte1&0x7F) in ~[50,67] almost always.
// fp32: byte1 = mantissa bits, uniform -> ~14% hit rate. Majority vote.
__global__ void k_detect_f(const unsigned* __restrict__ xw, int* __restrict__ flagB) {
    __shared__ int cs[4];
    int t = threadIdx.x;
    int c = 0;
    for (int i = t; i < 4096; i += 256) {
        unsigned v = (xw[i] >> 8) & 0x7F;
        if (v >= 50 && v <= 67) c++;
    }
    for (int o = 1; o < 64; o <<= 1) c += __shfl_xor(c, o);
    if ((t & 63) == 0) cs[t >> 6] = c;
    __syncthreads();
    if (t == 0) flagB[0] = (cs[0] + cs[1] + cs[2] + cs[3] > 2048) ? 1 : 0;
}

// Convert a float input (bf16 or fp32 storage, per flag) to canonical fp32.
__global__ void k_cvt(const void* __restrict__ src, float* __restrict__ dst, int n,
                      const int* __restrict__ flagB) {
    int i = blockIdx.x * 256 + threadIdx.x;
    if (i >= n) return;
    if (*flagB) dst[i] = b2f(((const unsigned short*)src)[i]);
    else        dst[i] = ((const float*)src)[i];
}

// ---------------- CSR build ----------------
__global__ void k_zero(int* p, int n) {
    int i = blockIdx.x * 256 + threadIdx.x;
    if (i < n) p[i] = 0;
}

__global__ void k_hist(const int* __restrict__ ei, const int* __restrict__ flagW,
                       int* __restrict__ cnt) {
    int i = blockIdx.x * 256 + threadIdx.x;
    if (i >= ET) return;
    bool w32 = (*flagW != 0);
    int d = (i < EE) ? (w32 ? ei[EE + i] : ei[2 * (EE + i)]) : (i - EE);
    atomicAdd(&cnt[d], 1);
}

static __device__ __forceinline__ int block_scan_incl(int v, int t, int* ws) {
    int lane = t & 63, w = t >> 6;
    int x = v;
    for (int o = 1; o < 64; o <<= 1) {
        int y = __shfl_up(x, o);
        if (lane >= o) x += y;
    }
    if (lane == 63) ws[w] = x;
    __syncthreads();
    if (t == 0) {
        int s = 0;
        for (int k = 0; k < 4; k++) { int tmp = ws[k]; ws[k] = s; s += tmp; }
    }
    __syncthreads();
    return x + ws[w];
}

__global__ void k_scan_a(const int* __restrict__ cnt, int* __restrict__ rowptr, int* __restrict__ bsum) {
    __shared__ int ws[4];
    int t = threadIdx.x, b = blockIdx.x;
    int i = b * 256 + t;
    int v = (i < NN) ? cnt[i] : 0;
    int incl = block_scan_incl(v, t, ws);
    if (i < NN) rowptr[i] = incl - v;
    if (t == 255) bsum[b] = incl;
}

__global__ void k_scan_b(int* __restrict__ bsum, int nb) {
    __shared__ int ws[4];
    int t = threadIdx.x;
    int v = (t < nb) ? bsum[t] : 0;
    int incl = block_scan_incl(v, t, ws);
    if (t < nb) bsum[t] = incl - v;
}

__global__ void k_scan_c(int* __restrict__ rowptr, const int* __restrict__ bsum, int* __restrict__ cursor) {
    int t = threadIdx.x, b = blockIdx.x;
    int i = b * 256 + t;
    if (i < NN) {
        int r = rowptr[i] + bsum[b];
        rowptr[i] = r;
        cursor[i] = r;
    }
    if (i == 0) rowptr[NN] = ET;
}

__global__ void k_scatter(const int* __restrict__ ei, const int* __restrict__ flagW,
                          int* __restrict__ cursor, int* __restrict__ esrc) {
    int i = blockIdx.x * 256 + threadIdx.x;
    if (i >= ET) return;
    bool w32 = (*flagW != 0);
    int s, d;
    if (i < EE) {
        if (w32) { s = ei[i];     d = ei[EE + i]; }
        else     { s = ei[2 * i]; d = ei[2 * (EE + i)]; }
    } else {
        s = d = i - EE;
    }
    int p = atomicAdd(&cursor[d], 1);
    esrc[p] = s;
}

// ---------------- simple VALU GEMM: C[M,NC] = A[M,K] @ W[K,NC], all fp32 ----------------
template<int NC>
__global__ __launch_bounds__(256) void k_gemm_s(const float* __restrict__ A,
                                                const float* __restrict__ W,
                                                float* __restrict__ C, int K) {
    __shared__ float Ar[4 * 256];
    int t = threadIdx.x;
    int row0 = blockIdx.x * 4;
    for (int idx = t; idx < 4 * K; idx += 256) {
        int r = idx / K, k = idx - r * K;
        Ar[r * 256 + k] = A[(size_t)(row0 + r) * K + k];
    }
    __syncthreads();
    if (NC == 256) {
        int c = t;
        float a0 = 0.f, a1 = 0.f, a2 = 0.f, a3 = 0.f;
        for (int k = 0; k < K; k++) {
            float w = W[(size_t)k * NC + c];
            a0 += Ar[0 * 256 + k] * w;
            a1 += Ar[1 * 256 + k] * w;
            a2 += Ar[2 * 256 + k] * w;
            a3 += Ar[3 * 256 + k] * w;
        }
        C[(size_t)(row0 + 0) * NC + c] = a0;
        C[(size_t)(row0 + 1) * NC + c] = a1;
        C[(size_t)(row0 + 2) * NC + c] = a2;
        C[(size_t)(row0 + 3) * NC + c] = a3;
    } else {
        int c = t & (NC - 1), r = t / NC;
        float a0 = 0.f;
        for (int k = 0; k < K; k++)
            a0 += Ar[r * 256 + k] * W[(size_t)k * NC + c];
        C[(size_t)(row0 + r) * NC + c] = a0;
    }
}

// ---------------- attention scores (4 heads, C=64) ----------------
__global__ void k_att4(const float* __restrict__ h,
                       const float* __restrict__ sa, const float* __restrict__ da,
                       float* __restrict__ asrc, float* __restrict__ adst) {
    int node = blockIdx.x * 4 + (threadIdx.x >> 6);
    if (node >= NN) return;
    int lane = threadIdx.x & 63;
    const float4 hv = *(const float4*)(h + (size_t)node * HID + lane * 4);
    const float4 su = *(const float4*)(sa + lane * 4);
    const float4 du = *(const float4*)(da + lane * 4);
    float ps = hv.x * su.x + hv.y * su.y + hv.z * su.z + hv.w * su.w;
    float pd = hv.x * du.x + hv.y * du.y + hv.z * du.z + hv.w * du.w;
    for (int o = 1; o < 16; o <<= 1) { ps += __shfl_xor(ps, o); pd += __shfl_xor(pd, o); }
    if ((lane & 15) == 0) {
        asrc[node * 4 + (lane >> 4)] = ps;
        adst[node * 4 + (lane >> 4)] = pd;
    }
}

// ---------------- attention scores (1 head, C=64) ----------------
__global__ void k_att1(const float* __restrict__ h,
                       const float* __restrict__ sa, const float* __restrict__ da,
                       float* __restrict__ asrc, float* __restrict__ adst) {
    int node = blockIdx.x * 4 + (threadIdx.x >> 6);
    if (node >= NN) return;
    int lane = threadIdx.x & 63;
    float hv = h[(size_t)node * OUTC + lane];
    float ps = hv * sa[lane];
    float pd = hv * da[lane];
    for (int o = 1; o < 64; o <<= 1) { ps += __shfl_xor(ps, o); pd += __shfl_xor(pd, o); }
    if (lane == 0) { asrc[node] = ps; adst[node] = pd; }
}

// ---------------- edge aggregation, 4 heads + bias + BN + ELU -> fp32 act ----------------
__global__ void k_agg4(const float* __restrict__ h,
                       const float* __restrict__ asrc, const float* __restrict__ adst,
                       const int* __restrict__ rowptr, const int* __restrict__ esrc,
                       const float* __restrict__ bias,
                       const float* __restrict__ bng, const float* __restrict__ bnb,
                       const float* __restrict__ bnm, const float* __restrict__ bnv,
                       float* __restrict__ act) {
    int node = blockIdx.x * 4 + (threadIdx.x >> 6);
    if (node >= NN) return;
    int lane = threadIdx.x & 63;
    int s0 = rowptr[node], s1 = rowptr[node + 1];
    int deg = s1 - s0;
    float4 ad = *(const float4*)(adst + (size_t)node * 4);

    float mx0 = -1e30f, mx1 = -1e30f, mx2 = -1e30f, mx3 = -1e30f;
    for (int i = lane; i < deg; i += 64) {
        int s = esrc[s0 + i];
        float4 as = *(const float4*)(asrc + (size_t)s * 4);
        mx0 = fmaxf(mx0, leaky(as.x + ad.x));
        mx1 = fmaxf(mx1, leaky(as.y + ad.y));
        mx2 = fmaxf(mx2, leaky(as.z + ad.z));
        mx3 = fmaxf(mx3, leaky(as.w + ad.w));
    }
    for (int o = 1; o < 64; o <<= 1) {
        mx0 = fmaxf(mx0, __shfl_xor(mx0, o));
        mx1 = fmaxf(mx1, __shfl_xor(mx1, o));
        mx2 = fmaxf(mx2, __shfl_xor(mx2, o));
        mx3 = fmaxf(mx3, __shfl_xor(mx3, o));
    }
    int hd = lane >> 4;
    float mh  = hd == 0 ? mx0  : hd == 1 ? mx1  : hd == 2 ? mx2  : mx3;
    float adh = hd == 0 ? ad.x : hd == 1 ? ad.y : hd == 2 ? ad.z : ad.w;

    float den = 0.f;
    float a0 = 0.f, a1 = 0.f, a2 = 0.f, a3 = 0.f;
    for (int i = 0; i < deg; i++) {
        int s = esrc[s0 + i];
        float4 as = *(const float4*)(asrc + (size_t)s * 4);
        float ash = hd == 0 ? as.x : hd == 1 ? as.y : hd == 2 ? as.z : as.w;
        float w = __expf(leaky(ash + adh) - mh);
        den += w;
        float4 hv = *(const float4*)(h + (size_t)s * HID + lane * 4);
        a0 += w * hv.x; a1 += w * hv.y; a2 += w * hv.z; a3 += w * hv.w;
    }
    float inv = 1.f / (den + 1e-16f);
    int c0 = lane * 4;
    float o[4] = {a0 * inv, a1 * inv, a2 * inv, a3 * inv};
    float res[4];
    for (int j = 0; j < 4; j++) {
        int c = c0 + j;
        float val = o[j] + bias[c];
        val = (val - bnm[c]) * rsqrtf(bnv[c] + BNEPS) * bng[c] + bnb[c];
        res[j] = val > 0.f ? val : expm1f(val);
    }
    *(float4*)(act + (size_t)node * HID + c0) = *(float4*)res;
}

// ---------------- edge aggregation, 1 head + bias -> output (dtype per flag) ----------------
__global__ void k_agg1(const float* __restrict__ h,
                       const float* __restrict__ asrc, const float* __restrict__ adst,
                       const int* __restrict__ rowptr, const int* __restrict__ esrc,
                       const float* __restrict__ bias,
                       void* __restrict__ outp, const int* __restrict__ flagB) {
    int node = blockIdx.x * 4 + (threadIdx.x >> 6);
    if (node >= NN) return;
    int lane = threadIdx.x & 63;
    int s0 = rowptr[node], s1 = rowptr[node + 1];
    int deg = s1 - s0;
    float ad = adst[node];

    float mx = -1e30f;
    for (int i = lane; i < deg; i += 64) {
        int s = esrc[s0 + i];
        mx = fmaxf(mx, leaky(asrc[s] + ad));
    }
    for (int o = 1; o < 64; o <<= 1) mx = fmaxf(mx, __shfl_xor(mx, o));

    float den = 0.f, acc = 0.f;
    for (int i = 0; i < deg; i++) {
        int s = esrc[s0 + i];
        float w = __expf(leaky(asrc[s] + ad) - mx);
        den += w;
        acc += w * h[(size_t)s * OUTC + lane];
    }
    float val = acc / (den + 1e-16f) + bias[lane];
    if (*flagB) ((unsigned short*)outp)[(size_t)node * OUTC + lane] = f2b(val);
    else        ((float*)outp)[(size_t)node * OUTC + lane] = val;
}

// ---------------- launch ----------------
extern "C" void kernel_launch(void* const* d_in, const int* in_sizes, int n_in,
                              void* d_out, int out_size, void* d_ws, size_t ws_size,
                              hipStream_t stream) {
    const void* x   = d_in[0];
    const int*  ei  = (const int*)d_in[1];
    const void* W0  = d_in[2];
    const void* as0 = d_in[3];
    const void* ad0 = d_in[4];
    const void* b0  = d_in[5];
    const void* g0  = d_in[6];
    const void* be0 = d_in[7];
    const void* m0  = d_in[8];
    const void* v0  = d_in[9];
    const void* W1  = d_in[10];
    const void* as1 = d_in[11];
    const void* ad1 = d_in[12];
    const void* b1  = d_in[13];
    const void* g1  = d_in[14];
    const void* be1 = d_in[15];
    const void* m1  = d_in[16];
    const void* v1  = d_in[17];
    const void* W2  = d_in[18];
    const void* as2 = d_in[19];
    const void* ad2 = d_in[20];
    const void* b2  = d_in[21];

    char* ws = (char*)d_ws;
    size_t off = 0;
    auto alloc = [&](size_t n) { void* p = ws + off; off += (n + 255) & ~(size_t)255; return p; };

    float* xx     = (float*)alloc((size_t)NN * INC * 4);     // 25.6 MB
    float* h      = (float*)alloc((size_t)NN * HID * 4);     // 51.2 MB
    float* act    = (float*)alloc((size_t)NN * HID * 4);     // 51.2 MB
    float* wf     = (float*)alloc((size_t)HID * HID * 4);    // 256 KB
    float* pp     = (float*)alloc((size_t)7 * 256 * 4);      // params: as,ad,b,g,be,m,v
    float* asrc   = (float*)alloc((size_t)NN * 4 * 4);
    float* adst   = (float*)alloc((size_t)NN * 4 * 4);
    int*   cnt    = (int*)alloc((size_t)(NN + 2) * 4);       // + flagW, flagB
    int*   rowptr = (int*)alloc((size_t)(NN + 1) * 4);
    int*   cursor = (int*)alloc((size_t)NN * 4);
    int*   esrc   = (int*)alloc((size_t)ET * 4);
    int*   bsum   = (int*)alloc(256 * 4);
    int*   flagW  = cnt + NN;
    int*   flagB  = cnt + NN + 1;

    const int nbN = (NN + 255) / 256;
    const int nbE = (ET + 255) / 256;
    const int nbW = (NN * 64 + 255) / 256;   // wave per node
    const int nbG = NN / 4;

    auto cvt = [&](const void* s, float* d, int n) {
        k_cvt<<<(n + 255) / 256, 256, 0, stream>>>(s, d, n, flagB);
    };

    // dtype detection + CSR build
    k_zero<<<nbN + 1, 256, 0, stream>>>(cnt, NN + 2);
    k_detect_w<<<256, 256, 0, stream>>>(ei, flagW);
    k_detect_f<<<1, 256, 0, stream>>>((const unsigned*)x, flagB);
    k_hist<<<nbE, 256, 0, stream>>>(ei, flagW, cnt);
    k_scan_a<<<nbN, 256, 0, stream>>>(cnt, rowptr, bsum);
    k_scan_b<<<1, 256, 0, stream>>>(bsum, nbN);
    k_scan_c<<<nbN, 256, 0, stream>>>(rowptr, bsum, cursor);
    k_scatter<<<nbE, 256, 0, stream>>>(ei, flagW, cursor, esrc);

    // ---- Layer 0: x[N,128] @ W0[128,256] ----
    cvt(x, xx, NN * INC);
    cvt(W0, wf, INC * HID);
    cvt(as0, pp + 0, 256);  cvt(ad0, pp + 256, 256);  cvt(b0, pp + 512, 256);
    cvt(g0, pp + 768, 256); cvt(be0, pp + 1024, 256); cvt(m0, pp + 1280, 256); cvt(v0, pp + 1536, 256);
    k_gemm_s<HID><<<nbG, 256, 0, stream>>>(xx, wf, h, INC);
    k_att4<<<nbW, 256, 0, stream>>>(h, pp + 0, pp + 256, asrc, adst);
    k_agg4<<<nbW, 256, 0, stream>>>(h, asrc, adst, rowptr, esrc,
                                    pp + 512, pp + 768, pp + 1024, pp + 1280, pp + 1536, act);

    // ---- Layer 1: act[N,256] @ W1[256,256] ----
    cvt(W1, wf, HID * HID);
    cvt(as1, pp + 0, 256);  cvt(ad1, pp + 256, 256);  cvt(b1, pp + 512, 256);
    cvt(g1, pp + 768, 256); cvt(be1, pp + 1024, 256); cvt(m1, pp + 1280, 256); cvt(v1, pp + 1536, 256);
    k_gemm_s<HID><<<nbG, 256, 0, stream>>>(act, wf, h, HID);
    k_att4<<<nbW, 256, 0, stream>>>(h, pp + 0, pp + 256, asrc, adst);
    k_agg4<<<nbW, 256, 0, stream>>>(h, asrc, adst, rowptr, esrc,
                                    pp + 512, pp + 768, pp + 1024, pp + 1280, pp + 1536, act);

    // ---- Layer 2: act[N,256] @ W2[256,64], heads=1, mean==identity ----
    cvt(W2, wf, HID * OUTC);
    cvt(as2, pp + 0, OUTC); cvt(ad2, pp + 256, OUTC); cvt(b2, pp + 512, OUTC);
    k_gemm_s<OUTC><<<nbG, 256, 0, stream>>>(act, wf, h, HID);
    k_att1<<<nbW, 256, 0, stream>>>(h, pp + 0, pp + 256, asrc, adst);
    k_agg1<<<nbW, 256, 0, stream>>>(h, asrc, adst, rowptr, esrc, pp + 512, d_out, flagB);
}

// Round 5
// 676.543 us; speedup vs baseline: 1.5648x; 1.5648x over previous
//
#include <hip/hip_runtime.h>

#define NN   50000
#define EE   800000
#define ET   850000          // EE + NN self loops
#define INC  128
#define HID  256
#define OUTC 64
#define NEG  0.2f
#define BNEPS 1e-5f

typedef __bf16 bf16x8 __attribute__((ext_vector_type(8)));
typedef float  f32x4  __attribute__((ext_vector_type(4)));

static __device__ __forceinline__ float b2f(unsigned short u) {
    return __uint_as_float(((unsigned)u) << 16);
}
static __device__ __forceinline__ unsigned short f2b(float f) {
    unsigned u = __float_as_uint(f);
    unsigned r = u + 0x7FFFu + ((u >> 16) & 1u);
    return (unsigned short)(r >> 16);
}
static __device__ __forceinline__ float leaky(float x) {
    return x > 0.f ? x : NEG * x;
}

// ---------------- dtype detection ----------------
__global__ void k_detect_w(const int* __restrict__ ei, int* __restrict__ flagW) {
    int i = blockIdx.x * 256 + threadIdx.x;
    if (i < 65536 && ei[2 * i + 1] != 0) atomicOr(flagW, 1);
}

__global__ void k_detect_f(const unsigned* __restrict__ xw, int* __restrict__ flagB) {
    __shared__ int cs[4];
    int t = threadIdx.x;
    int c = 0;
    for (int i = t; i < 4096; i += 256) {
        unsigned v = (xw[i] >> 8) & 0x7F;
        if (v >= 50 && v <= 67) c++;
    }
    for (int o = 1; o < 64; o <<= 1) c += __shfl_xor(c, o);
    if ((t & 63) == 0) cs[t >> 6] = c;
    __syncthreads();
    if (t == 0) flagB[0] = (cs[0] + cs[1] + cs[2] + cs[3] > 2048) ? 1 : 0;
}

// float input (bf16 or fp32 storage) -> canonical fp32
__global__ void k_cvt(const void* __restrict__ src, float* __restrict__ dst, int n,
                      const int* __restrict__ flagB) {
    int i = blockIdx.x * 256 + threadIdx.x;
    if (i >= n) return;
    if (*flagB) dst[i] = b2f(((const unsigned short*)src)[i]);
    else        dst[i] = ((const float*)src)[i];
}

// float input -> canonical bf16
__global__ void k_cvt_b(const void* __restrict__ src, unsigned short* __restrict__ dst, int n,
                        const int* __restrict__ flagB) {
    int i = blockIdx.x * 256 + threadIdx.x;
    if (i >= n) return;
    if (*flagB) dst[i] = ((const unsigned short*)src)[i];
    else        dst[i] = f2b(((const float*)src)[i]);
}

// W[K,NC] (either storage) -> WT[NC,K] bf16
__global__ void k_transp_b(const void* __restrict__ W, unsigned short* __restrict__ WT,
                           int K, int NC, const int* __restrict__ flagB) {
    int i = blockIdx.x * 256 + threadIdx.x;
    if (i >= K * NC) return;
    int k = i / NC, n = i - k * NC;
    unsigned short v = *flagB ? ((const unsigned short*)W)[i] : f2b(((const float*)W)[i]);
    WT[n * K + k] = v;
}

// ---------------- CSR build ----------------
__global__ void k_zero(int* p, int n) {
    int i = blockIdx.x * 256 + threadIdx.x;
    if (i < n) p[i] = 0;
}

__global__ void k_hist(const int* __restrict__ ei, const int* __restrict__ flagW,
                       int* __restrict__ cnt) {
    int i = blockIdx.x * 256 + threadIdx.x;
    if (i >= ET) return;
    bool w32 = (*flagW != 0);
    int d = (i < EE) ? (w32 ? ei[EE + i] : ei[2 * (EE + i)]) : (i - EE);
    atomicAdd(&cnt[d], 1);
}

static __device__ __forceinline__ int block_scan_incl(int v, int t, int* ws) {
    int lane = t & 63, w = t >> 6;
    int x = v;
    for (int o = 1; o < 64; o <<= 1) {
        int y = __shfl_up(x, o);
        if (lane >= o) x += y;
    }
    if (lane == 63) ws[w] = x;
    __syncthreads();
    if (t == 0) {
        int s = 0;
        for (int k = 0; k < 4; k++) { int tmp = ws[k]; ws[k] = s; s += tmp; }
    }
    __syncthreads();
    return x + ws[w];
}

__global__ void k_scan_a(const int* __restrict__ cnt, int* __restrict__ rowptr, int* __restrict__ bsum) {
    __shared__ int ws[4];
    int t = threadIdx.x, b = blockIdx.x;
    int i = b * 256 + t;
    int v = (i < NN) ? cnt[i] : 0;
    int incl = block_scan_incl(v, t, ws);
    if (i < NN) rowptr[i] = incl - v;
    if (t == 255) bsum[b] = incl;
}

__global__ void k_scan_b(int* __restrict__ bsum, int nb) {
    __shared__ int ws[4];
    int t = threadIdx.x;
    int v = (t < nb) ? bsum[t] : 0;
    int incl = block_scan_incl(v, t, ws);
    if (t < nb) bsum[t] = incl - v;
}

__global__ void k_scan_c(int* __restrict__ rowptr, const int* __restrict__ bsum, int* __restrict__ cursor) {
    int t = threadIdx.x, b = blockIdx.x;
    int i = b * 256 + t;
    if (i < NN) {
        int r = rowptr[i] + bsum[b];
        rowptr[i] = r;
        cursor[i] = r;
    }
    if (i == 0) rowptr[NN] = ET;
}

__global__ void k_scatter(const int* __restrict__ ei, const int* __restrict__ flagW,
                          int* __restrict__ cursor, int* __restrict__ esrc) {
    int i = blockIdx.x * 256 + threadIdx.x;
    if (i >= ET) return;
    bool w32 = (*flagW != 0);
    int s, d;
    if (i < EE) {
        if (w32) { s = ei[i];     d = ei[EE + i]; }
        else     { s = ei[2 * i]; d = ei[2 * (EE + i)]; }
    } else {
        s = d = i - EE;
    }
    int p = atomicAdd(&cursor[d], 1);
    esrc[p] = s;
}

// ---------------- MFMA GEMM: h[M,NC](fp32) = A[M,K](bf16) @ W via WT[NC,K](bf16) ----------------
__global__ __launch_bounds__(256) void k_gemm(const unsigned short* __restrict__ A,
                                              const unsigned short* __restrict__ WT,
                                              float* __restrict__ C,
                                              int M, int K, int NC) {
    __shared__ __align__(16) unsigned short As[128 * 40];
    __shared__ __align__(16) unsigned short Bs[64 * 40];
    int t = threadIdx.x;
    int bm = blockIdx.x, bn = blockIdx.y;
    int lane = t & 63, wave = t >> 6;
    int m16 = lane & 15, quad = lane >> 4;

    f32x4 acc[2][4];
    for (int a = 0; a < 2; a++) for (int b = 0; b < 4; b++) acc[a][b] = (f32x4){0.f, 0.f, 0.f, 0.f};

    int arow = t >> 1, ahalf = t & 1;    // 2 threads/row cover 32 elems (2 x uint4 each)
    int brow = t >> 2, bq = t & 3;       // 4 threads/row cover 32 elems (1 x uint4 each)
    long gArow = (long)bm * 128 + arow;

    for (int k0 = 0; k0 < K; k0 += 32) {
        uint4 av0 = {0u, 0u, 0u, 0u}, av1 = {0u, 0u, 0u, 0u};
        if (gArow < M) {
            const unsigned short* ap = A + gArow * (size_t)K + k0 + ahalf * 16;
            av0 = *(const uint4*)(ap);
            av1 = *(const uint4*)(ap + 8);
        }
        uint4 bv = *(const uint4*)(WT + ((size_t)bn * 64 + brow) * K + k0 + bq * 8);
        *(uint4*)&As[arow * 40 + ahalf * 16]     = av0;
        *(uint4*)&As[arow * 40 + ahalf * 16 + 8] = av1;
        *(uint4*)&Bs[brow * 40 + bq * 8]         = bv;
        __syncthreads();
        int wrow = wave * 32;
        bf16x8 af[2], bf[4];
        for (int mt = 0; mt < 2; mt++)
            af[mt] = *(const bf16x8*)&As[(wrow + mt * 16 + m16) * 40 + quad * 8];
        for (int nt = 0; nt < 4; nt++)
            bf[nt] = *(const bf16x8*)&Bs[(nt * 16 + m16) * 40 + quad * 8];
        for (int mt = 0; mt < 2; mt++)
            for (int nt = 0; nt < 4; nt++)
                acc[mt][nt] = __builtin_amdgcn_mfma_f32_16x16x32_bf16(af[mt], bf[nt], acc[mt][nt], 0, 0, 0);
        __syncthreads();
    }

    // C/D layout: col = lane&15, row = quad*4 + reg
    for (int mt = 0; mt < 2; mt++) {
        int gR0 = bm * 128 + wave * 32 + mt * 16 + quad * 4;
        for (int nt = 0; nt < 4; nt++) {
            int gC = bn * 64 + nt * 16 + m16;
            for (int r = 0; r < 4; r++) {
                int gR = gR0 + r;
                if (gR < M) C[(size_t)gR * NC + gC] = acc[mt][nt][r];
            }
        }
    }
}

// ---------------- attention scores (4 heads, C=64) ----------------
__global__ void k_att4(const float* __restrict__ h,
                       const float* __restrict__ sa, const float* __restrict__ da,
                       float* __restrict__ asrc, float* __restrict__ adst) {
    int node = blockIdx.x * 4 + (threadIdx.x >> 6);
    if (node >= NN) return;
    int lane = threadIdx.x & 63;
    const float4 hv = *(const float4*)(h + (size_t)node * HID + lane * 4);
    const float4 su = *(const float4*)(sa + lane * 4);
    const float4 du = *(const float4*)(da + lane * 4);
    float ps = hv.x * su.x + hv.y * su.y + hv.z * su.z + hv.w * su.w;
    float pd = hv.x * du.x + hv.y * du.y + hv.z * du.z + hv.w * du.w;
    for (int o = 1; o < 16; o <<= 1) { ps += __shfl_xor(ps, o); pd += __shfl_xor(pd, o); }
    if ((lane & 15) == 0) {
        asrc[node * 4 + (lane >> 4)] = ps;
        adst[node * 4 + (lane >> 4)] = pd;
    }
}

// ---------------- attention scores (1 head, C=64) ----------------
__global__ void k_att1(const float* __restrict__ h,
                       const float* __restrict__ sa, const float* __restrict__ da,
                       float* __restrict__ asrc, float* __restrict__ adst) {
    int node = blockIdx.x * 4 + (threadIdx.x >> 6);
    if (node >= NN) return;
    int lane = threadIdx.x & 63;
    float hv = h[(size_t)node * OUTC + lane];
    float ps = hv * sa[lane];
    float pd = hv * da[lane];
    for (int o = 1; o < 64; o <<= 1) { ps += __shfl_xor(ps, o); pd += __shfl_xor(pd, o); }
    if (lane == 0) { asrc[node] = ps; adst[node] = pd; }
}

// ---------------- edge aggregation, 4 heads + bias + BN + ELU -> bf16 act ----------------
__global__ void k_agg4(const float* __restrict__ h,
                       const float* __restrict__ asrc, const float* __restrict__ adst,
                       const int* __restrict__ rowptr, const int* __restrict__ esrc,
                       const float* __restrict__ bias,
                       const float* __restrict__ bng, const float* __restrict__ bnb,
                       const float* __restrict__ bnm, const float* __restrict__ bnv,
                       unsigned short* __restrict__ act) {
    int node = blockIdx.x * 4 + (threadIdx.x >> 6);
    if (node >= NN) return;
    int lane = threadIdx.x & 63;
    int e0 = rowptr[node], e1 = rowptr[node + 1];
    int deg = e1 - e0;
    float4 ad = *(const float4*)(adst + (size_t)node * 4);

    float mx0 = -1e30f, mx1 = -1e30f, mx2 = -1e30f, mx3 = -1e30f;
    for (int i = lane; i < deg; i += 64) {
        int s = esrc[e0 + i];
        float4 as = *(const float4*)(asrc + (size_t)s * 4);
        mx0 = fmaxf(mx0, leaky(as.x + ad.x));
        mx1 = fmaxf(mx1, leaky(as.y + ad.y));
        mx2 = fmaxf(mx2, leaky(as.z + ad.z));
        mx3 = fmaxf(mx3, leaky(as.w + ad.w));
    }
    for (int o = 1; o < 64; o <<= 1) {
        mx0 = fmaxf(mx0, __shfl_xor(mx0, o));
        mx1 = fmaxf(mx1, __shfl_xor(mx1, o));
        mx2 = fmaxf(mx2, __shfl_xor(mx2, o));
        mx3 = fmaxf(mx3, __shfl_xor(mx3, o));
    }
    int hd = lane >> 4;
    float mh  = hd == 0 ? mx0  : hd == 1 ? mx1  : hd == 2 ? mx2  : mx3;
    float adh = hd == 0 ? ad.x : hd == 1 ? ad.y : hd == 2 ? ad.z : ad.w;

    float den = 0.f;
    float a0 = 0.f, a1 = 0.f, a2 = 0.f, a3 = 0.f;
    const size_t lc = (size_t)lane * 4;
    int i = 0;
    // 4-way unrolled: 4 independent 1KB gathers in flight per wave
    for (; i + 4 <= deg; i += 4) {
        int sA = esrc[e0 + i], sB = esrc[e0 + i + 1], sC = esrc[e0 + i + 2], sD = esrc[e0 + i + 3];
        float4 aA = *(const float4*)(asrc + (size_t)sA * 4);
        float4 aB = *(const float4*)(asrc + (size_t)sB * 4);
        float4 aC = *(const float4*)(asrc + (size_t)sC * 4);
        float4 aD = *(const float4*)(asrc + (size_t)sD * 4);
        float4 hA = *(const float4*)(h + (size_t)sA * HID + lc);
        float4 hB = *(const float4*)(h + (size_t)sB * HID + lc);
        float4 hC = *(const float4*)(h + (size_t)sC * HID + lc);
        float4 hD = *(const float4*)(h + (size_t)sD * HID + lc);
        float eA = hd == 0 ? aA.x : hd == 1 ? aA.y : hd == 2 ? aA.z : aA.w;
        float eB = hd == 0 ? aB.x : hd == 1 ? aB.y : hd == 2 ? aB.z : aB.w;
        float eC = hd == 0 ? aC.x : hd == 1 ? aC.y : hd == 2 ? aC.z : aC.w;
        float eD = hd == 0 ? aD.x : hd == 1 ? aD.y : hd == 2 ? aD.z : aD.w;
        float wA = __expf(leaky(eA + adh) - mh);
        float wB = __expf(leaky(eB + adh) - mh);
        float wC = __expf(leaky(eC + adh) - mh);
        float wD = __expf(leaky(eD + adh) - mh);
        den += wA + wB + wC + wD;
        a0 += wA * hA.x + wB * hB.x + wC * hC.x + wD * hD.x;
        a1 += wA * hA.y + wB * hB.y + wC * hC.y + wD * hD.y;
        a2 += wA * hA.z + wB * hB.z + wC * hC.z + wD * hD.z;
        a3 += wA * hA.w + wB * hB.w + wC * hC.w + wD * hD.w;
    }
    for (; i < deg; i++) {
        int s = esrc[e0 + i];
        float4 as = *(const float4*)(asrc + (size_t)s * 4);
        float e = hd == 0 ? as.x : hd == 1 ? as.y : hd == 2 ? as.z : as.w;
        float w = __expf(leaky(e + adh) - mh);
        den += w;
        float4 hv = *(const float4*)(h + (size_t)s * HID + lc);
        a0 += w * hv.x; a1 += w * hv.y; a2 += w * hv.z; a3 += w * hv.w;
    }
    float inv = 1.f / (den + 1e-16f);
    int c0 = lane * 4;
    float o[4] = {a0 * inv, a1 * inv, a2 * inv, a3 * inv};
    unsigned short res[4];
    for (int j = 0; j < 4; j++) {
        int c = c0 + j;
        float val = o[j] + bias[c];
        val = (val - bnm[c]) * rsqrtf(bnv[c] + BNEPS) * bng[c] + bnb[c];
        val = val > 0.f ? val : expm1f(val);
        res[j] = f2b(val);
    }
    *(ushort4*)(act + (size_t)node * HID + c0) = *(ushort4*)res;
}

// ---------------- edge aggregation, 1 head + bias -> output ----------------
__global__ void k_agg1(const float* __restrict__ h,
                       const float* __restrict__ asrc, const float* __restrict__ adst,
                       const int* __restrict__ rowptr, const int* __restrict__ esrc,
                       const float* __restrict__ bias,
                       void* __restrict__ outp, const int* __restrict__ flagB) {
    int node = blockIdx.x * 4 + (threadIdx.x >> 6);
    if (node >= NN) return;
    int lane = threadIdx.x & 63;
    int e0 = rowptr[node], e1 = rowptr[node + 1];
    int deg = e1 - e0;
    float ad = adst[node];

    float mx = -1e30f;
    for (int i = lane; i < deg; i += 64) {
        int s = esrc[e0 + i];
        mx = fmaxf(mx, leaky(asrc[s] + ad));
    }
    for (int o = 1; o < 64; o <<= 1) mx = fmaxf(mx, __shfl_xor(mx, o));

    float den = 0.f, acc = 0.f;
    int i = 0;
    for (; i + 4 <= deg; i += 4) {
        int sA = esrc[e0 + i], sB = esrc[e0 + i + 1], sC = esrc[e0 + i + 2], sD = esrc[e0 + i + 3];
        float eA = asrc[sA], eB = asrc[sB], eC = asrc[sC], eD = asrc[sD];
        float hA = h[(size_t)sA * OUTC + lane];
        float hB = h[(size_t)sB * OUTC + lane];
        float hC = h[(size_t)sC * OUTC + lane];
        float hD = h[(size_t)sD * OUTC + lane];
        float wA = __expf(leaky(eA + ad) - mx);
        float wB = __expf(leaky(eB + ad) - mx);
        float wC = __expf(leaky(eC + ad) - mx);
        float wD = __expf(leaky(eD + ad) - mx);
        den += wA + wB + wC + wD;
        acc += wA * hA + wB * hB + wC * hC + wD * hD;
    }
    for (; i < deg; i++) {
        int s = esrc[e0 + i];
        float w = __expf(leaky(asrc[s] + ad) - mx);
        den += w;
        acc += w * h[(size_t)s * OUTC + lane];
    }
    float val = acc / (den + 1e-16f) + bias[lane];
    if (*flagB) ((unsigned short*)outp)[(size_t)node * OUTC + lane] = f2b(val);
    else        ((float*)outp)[(size_t)node * OUTC + lane] = val;
}

// ---------------- launch ----------------
extern "C" void kernel_launch(void* const* d_in, const int* in_sizes, int n_in,
                              void* d_out, int out_size, void* d_ws, size_t ws_size,
                              hipStream_t stream) {
    const void* x   = d_in[0];
    const int*  ei  = (const int*)d_in[1];
    const void* W0  = d_in[2];
    const void* as0 = d_in[3];
    const void* ad0 = d_in[4];
    const void* b0  = d_in[5];
    const void* g0  = d_in[6];
    const void* be0 = d_in[7];
    const void* m0  = d_in[8];
    const void* v0  = d_in[9];
    const void* W1  = d_in[10];
    const void* as1 = d_in[11];
    const void* ad1 = d_in[12];
    const void* b1  = d_in[13];
    const void* g1  = d_in[14];
    const void* be1 = d_in[15];
    const void* m1  = d_in[16];
    const void* v1  = d_in[17];
    const void* W2  = d_in[18];
    const void* as2 = d_in[19];
    const void* ad2 = d_in[20];
    const void* b2  = d_in[21];

    char* ws = (char*)d_ws;
    size_t off = 0;
    auto alloc = [&](size_t n) { void* p = ws + off; off += (n + 255) & ~(size_t)255; return p; };

    unsigned short* xb  = (unsigned short*)alloc((size_t)NN * INC * 2);   // 12.8 MB
    float*          h   = (float*)alloc((size_t)NN * HID * 4);            // 51.2 MB
    unsigned short* act = (unsigned short*)alloc((size_t)NN * HID * 2);   // 25.6 MB
    unsigned short* WT  = (unsigned short*)alloc((size_t)HID * HID * 2);  // 128 KB
    float*          pp  = (float*)alloc((size_t)7 * 256 * 4);
    float*  asrc   = (float*)alloc((size_t)NN * 4 * 4);
    float*  adst   = (float*)alloc((size_t)NN * 4 * 4);
    int*    cnt    = (int*)alloc((size_t)(NN + 2) * 4);
    int*    rowptr = (int*)alloc((size_t)(NN + 1) * 4);
    int*    cursor = (int*)alloc((size_t)NN * 4);
    int*    esrc   = (int*)alloc((size_t)ET * 4);
    int*    bsum   = (int*)alloc(256 * 4);
    int*    flagW  = cnt + NN;
    int*    flagB  = cnt + NN + 1;

    const int nbN = (NN + 255) / 256;
    const int nbE = (ET + 255) / 256;
    const int nbW = (NN * 64 + 255) / 256;   // wave per node
    dim3 gemmGrid0((NN + 127) / 128, HID / 64);
    dim3 gemmGrid2((NN + 127) / 128, OUTC / 64);

    auto cvt = [&](const void* s, float* d, int n) {
        k_cvt<<<(n + 255) / 256, 256, 0, stream>>>(s, d, n, flagB);
    };

    // dtype detection + CSR build
    k_zero<<<nbN + 1, 256, 0, stream>>>(cnt, NN + 2);
    k_detect_w<<<256, 256, 0, stream>>>(ei, flagW);
    k_detect_f<<<1, 256, 0, stream>>>((const unsigned*)x, flagB);
    k_hist<<<nbE, 256, 0, stream>>>(ei, flagW, cnt);
    k_scan_a<<<nbN, 256, 0, stream>>>(cnt, rowptr, bsum);
    k_scan_b<<<1, 256, 0, stream>>>(bsum, nbN);
    k_scan_c<<<nbN, 256, 0, stream>>>(rowptr, bsum, cursor);
    k_scatter<<<nbE, 256, 0, stream>>>(ei, flagW, cursor, esrc);

    // ---- Layer 0: x[N,128] @ W0[128,256] ----
    k_cvt_b<<<(NN * INC + 255) / 256, 256, 0, stream>>>(x, xb, NN * INC, flagB);
    k_transp_b<<<(INC * HID + 255) / 256, 256, 0, stream>>>(W0, WT, INC, HID, flagB);
    cvt(as0, pp + 0, 256);  cvt(ad0, pp + 256, 256);  cvt(b0, pp + 512, 256);
    cvt(g0, pp + 768, 256); cvt(be0, pp + 1024, 256); cvt(m0, pp + 1280, 256); cvt(v0, pp + 1536, 256);
    k_gemm<<<gemmGrid0, 256, 0, stream>>>(xb, WT, h, NN, INC, HID);
    k_att4<<<nbW, 256, 0, stream>>>(h, pp + 0, pp + 256, asrc, adst);
    k_agg4<<<nbW, 256, 0, stream>>>(h, asrc, adst, rowptr, esrc,
                                    pp + 512, pp + 768, pp + 1024, pp + 1280, pp + 1536, act);

    // ---- Layer 1: act[N,256] @ W1[256,256] ----
    k_transp_b<<<(HID * HID + 255) / 256, 256, 0, stream>>>(W1, WT, HID, HID, flagB);
    cvt(as1, pp + 0, 256);  cvt(ad1, pp + 256, 256);  cvt(b1, pp + 512, 256);
    cvt(g1, pp + 768, 256); cvt(be1, pp + 1024, 256); cvt(m1, pp + 1280, 256); cvt(v1, pp + 1536, 256);
    k_gemm<<<gemmGrid0, 256, 0, stream>>>(act, WT, h, NN, HID, HID);
    k_att4<<<nbW, 256, 0, stream>>>(h, pp + 0, pp + 256, asrc, adst);
    k_agg4<<<nbW, 256, 0, stream>>>(h, asrc, adst, rowptr, esrc,
                                    pp + 512, pp + 768, pp + 1024, pp + 1280, pp + 1536, act);

    // ---- Layer 2: act[N,256] @ W2[256,64], heads=1, mean==identity ----
    k_transp_b<<<(HID * OUTC + 255) / 256, 256, 0, stream>>>(W2, WT, HID, OUTC, flagB);
    cvt(as2, pp + 0, OUTC); cvt(ad2, pp + 256, OUTC); cvt(b2, pp + 512, OUTC);
    k_gemm<<<gemmGrid2, 256, 0, stream>>>(act, WT, h, NN, HID, OUTC);
    k_att1<<<nbW, 256, 0, stream>>>(h, pp + 0, pp + 256, asrc, adst);
    k_agg1<<<nbW, 256, 0, stream>>>(h, asrc, adst, rowptr, esrc, pp + 512, d_out, flagB);
}

// Round 6
// 656.512 us; speedup vs baseline: 1.6126x; 1.0305x over previous
//
#include <hip/hip_runtime.h>

#define NN   50000
#define EE   800000
#define ET   850000          // EE + NN self loops
#define INC  128
#define HID  256
#define OUTC 64
#define NEG  0.2f
#define BNEPS 1e-5f

typedef __bf16 bf16x8 __attribute__((ext_vector_type(8)));
typedef float  f32x4  __attribute__((ext_vector_type(4)));

static __device__ __forceinline__ float b2f(unsigned short u) {
    return __uint_as_float(((unsigned)u) << 16);
}
static __device__ __forceinline__ unsigned short f2b(float f) {
    unsigned u = __float_as_uint(f);
    unsigned r = u + 0x7FFFu + ((u >> 16) & 1u);
    return (unsigned short)(r >> 16);
}
static __device__ __forceinline__ float leaky(float x) {
    return x > 0.f ? x : NEG * x;
}

// ---------------- dtype detection ----------------
__global__ void k_detect_w(const int* __restrict__ ei, int* __restrict__ flagW) {
    int i = blockIdx.x * 256 + threadIdx.x;
    if (i < 65536 && ei[2 * i + 1] != 0) atomicOr(flagW, 1);
}

__global__ void k_detect_f(const unsigned* __restrict__ xw, int* __restrict__ flagB) {
    __shared__ int cs[4];
    int t = threadIdx.x;
    int c = 0;
    for (int i = t; i < 4096; i += 256) {
        unsigned v = (xw[i] >> 8) & 0x7F;
        if (v >= 50 && v <= 67) c++;
    }
    for (int o = 1; o < 64; o <<= 1) c += __shfl_xor(c, o);
    if ((t & 63) == 0) cs[t >> 6] = c;
    __syncthreads();
    if (t == 0) flagB[0] = (cs[0] + cs[1] + cs[2] + cs[3] > 2048) ? 1 : 0;
}

// float input -> canonical bf16 (for GEMM A operand)
__global__ void k_cvt_b(const void* __restrict__ src, unsigned short* __restrict__ dst, int n,
                        const int* __restrict__ flagB) {
    int i = blockIdx.x * 256 + threadIdx.x;
    if (i >= n) return;
    if (*flagB) dst[i] = ((const unsigned short*)src)[i];
    else        dst[i] = f2b(((const float*)src)[i]);
}

// W[K,NC] (either storage) -> WT[NC,K] bf16
__global__ void k_transp_b(const void* __restrict__ W, unsigned short* __restrict__ WT,
                           int K, int NC, const int* __restrict__ flagB) {
    int i = blockIdx.x * 256 + threadIdx.x;
    if (i >= K * NC) return;
    int k = i / NC, n = i - k * NC;
    unsigned short v = *flagB ? ((const unsigned short*)W)[i] : f2b(((const float*)W)[i]);
    WT[n * K + k] = v;
}

// All 17 small param arrays -> fp32 pp buffer in ONE launch.
// pp layout: [0..7*256) layer0 {as,ad,b,g,be,m,v}, [7*256..14*256) layer1,
// [14*256..14*256+3*64) layer2 {as2,ad2,b2}.
__global__ void k_params(const void* p0, const void* p1, const void* p2, const void* p3,
                         const void* p4, const void* p5, const void* p6, const void* p7,
                         const void* p8, const void* p9, const void* p10, const void* p11,
                         const void* p12, const void* p13, const void* p14, const void* p15,
                         const void* p16,
                         float* __restrict__ pp, const int* __restrict__ flagB) {
    const void* srcs[17] = {p0,p1,p2,p3,p4,p5,p6,p7,p8,p9,p10,p11,p12,p13,p14,p15,p16};
    int b = blockIdx.x;           // 0..14 -> layer0/1 (256 each); 15 -> layer2 (3x64)
    int t = threadIdx.x;
    bool bf = (*flagB != 0);
    if (b < 14) {
        const void* s = srcs[b];
        float v = bf ? b2f(((const unsigned short*)s)[t]) : ((const float*)s)[t];
        pp[b * 256 + t] = v;
    } else if (t < 192) {
        int arr = t >> 6, j = t & 63;
        const void* s = srcs[14 + arr];
        float v = bf ? b2f(((const unsigned short*)s)[j]) : ((const float*)s)[j];
        pp[14 * 256 + arr * 64 + j] = v;
    }
}

// ---------------- CSR build ----------------
__global__ void k_zero(int* p, int n) {
    int i = blockIdx.x * 256 + threadIdx.x;
    if (i < n) p[i] = 0;
}

__global__ void k_hist(const int* __restrict__ ei, const int* __restrict__ flagW,
                       int* __restrict__ cnt) {
    int i = blockIdx.x * 256 + threadIdx.x;
    if (i >= ET) return;
    bool w32 = (*flagW != 0);
    int d = (i < EE) ? (w32 ? ei[EE + i] : ei[2 * (EE + i)]) : (i - EE);
    atomicAdd(&cnt[d], 1);
}

static __device__ __forceinline__ int block_scan_incl(int v, int t, int* ws) {
    int lane = t & 63, w = t >> 6;
    int x = v;
    for (int o = 1; o < 64; o <<= 1) {
        int y = __shfl_up(x, o);
        if (lane >= o) x += y;
    }
    if (lane == 63) ws[w] = x;
    __syncthreads();
    if (t == 0) {
        int s = 0;
        for (int k = 0; k < 4; k++) { int tmp = ws[k]; ws[k] = s; s += tmp; }
    }
    __syncthreads();
    return x + ws[w];
}

__global__ void k_scan_a(const int* __restrict__ cnt, int* __restrict__ rowptr, int* __restrict__ bsum) {
    __shared__ int ws[4];
    int t = threadIdx.x, b = blockIdx.x;
    int i = b * 256 + t;
    int v = (i < NN) ? cnt[i] : 0;
    int incl = block_scan_incl(v, t, ws);
    if (i < NN) rowptr[i] = incl - v;
    if (t == 255) bsum[b] = incl;
}

__global__ void k_scan_b(int* __restrict__ bsum, int nb) {
    __shared__ int ws[4];
    int t = threadIdx.x;
    int v = (t < nb) ? bsum[t] : 0;
    int incl = block_scan_incl(v, t, ws);
    if (t < nb) bsum[t] = incl - v;
}

__global__ void k_scan_c(int* __restrict__ rowptr, const int* __restrict__ bsum, int* __restrict__ cursor) {
    int t = threadIdx.x, b = blockIdx.x;
    int i = b * 256 + t;
    if (i < NN) {
        int r = rowptr[i] + bsum[b];
        rowptr[i] = r;
        cursor[i] = r;
    }
    if (i == 0) rowptr[NN] = ET;
}

__global__ void k_scatter(const int* __restrict__ ei, const int* __restrict__ flagW,
                          int* __restrict__ cursor, int* __restrict__ esrc) {
    int i = blockIdx.x * 256 + threadIdx.x;
    if (i >= ET) return;
    bool w32 = (*flagW != 0);
    int s, d;
    if (i < EE) {
        if (w32) { s = ei[i];     d = ei[EE + i]; }
        else     { s = ei[2 * i]; d = ei[2 * (EE + i)]; }
    } else {
        s = d = i - EE;
    }
    int p = atomicAdd(&cursor[d], 1);
    esrc[p] = s;
}

// ---------------- MFMA GEMM: h[M,NC](fp32) = A[M,K](bf16) @ W via WT[NC,K](bf16) ----------------
__global__ __launch_bounds__(256) void k_gemm(const unsigned short* __restrict__ A,
                                              const unsigned short* __restrict__ WT,
                                              float* __restrict__ C,
                                              int M, int K, int NC) {
    __shared__ __align__(16) unsigned short As[128 * 40];
    __shared__ __align__(16) unsigned short Bs[64 * 40];
    int t = threadIdx.x;
    int bm = blockIdx.x, bn = blockIdx.y;
    int lane = t & 63, wave = t >> 6;
    int m16 = lane & 15, quad = lane >> 4;

    f32x4 acc[2][4];
    for (int a = 0; a < 2; a++) for (int b = 0; b < 4; b++) acc[a][b] = (f32x4){0.f, 0.f, 0.f, 0.f};

    int arow = t >> 1, ahalf = t & 1;
    int brow = t >> 2, bq = t & 3;
    long gArow = (long)bm * 128 + arow;

    for (int k0 = 0; k0 < K; k0 += 32) {
        uint4 av0 = {0u, 0u, 0u, 0u}, av1 = {0u, 0u, 0u, 0u};
        if (gArow < M) {
            const unsigned short* ap = A + gArow * (size_t)K + k0 + ahalf * 16;
            av0 = *(const uint4*)(ap);
            av1 = *(const uint4*)(ap + 8);
        }
        uint4 bv = *(const uint4*)(WT + ((size_t)bn * 64 + brow) * K + k0 + bq * 8);
        *(uint4*)&As[arow * 40 + ahalf * 16]     = av0;
        *(uint4*)&As[arow * 40 + ahalf * 16 + 8] = av1;
        *(uint4*)&Bs[brow * 40 + bq * 8]         = bv;
        __syncthreads();
        int wrow = wave * 32;
        bf16x8 af[2], bf[4];
        for (int mt = 0; mt < 2; mt++)
            af[mt] = *(const bf16x8*)&As[(wrow + mt * 16 + m16) * 40 + quad * 8];
        for (int nt = 0; nt < 4; nt++)
            bf[nt] = *(const bf16x8*)&Bs[(nt * 16 + m16) * 40 + quad * 8];
        for (int mt = 0; mt < 2; mt++)
            for (int nt = 0; nt < 4; nt++)
                acc[mt][nt] = __builtin_amdgcn_mfma_f32_16x16x32_bf16(af[mt], bf[nt], acc[mt][nt], 0, 0, 0);
        __syncthreads();
    }

    for (int mt = 0; mt < 2; mt++) {
        int gR0 = bm * 128 + wave * 32 + mt * 16 + quad * 4;
        for (int nt = 0; nt < 4; nt++) {
            int gC = bn * 64 + nt * 16 + m16;
            for (int r = 0; r < 4; r++) {
                int gR = gR0 + r;
                if (gR < M) C[(size_t)gR * NC + gC] = acc[mt][nt][r];
            }
        }
    }
}

// ---------------- attention scores (4 heads, C=64) ----------------
__global__ void k_att4(const float* __restrict__ h,
                       const float* __restrict__ sa, const float* __restrict__ da,
                       float* __restrict__ asrc, float* __restrict__ adst) {
    int node = blockIdx.x * 4 + (threadIdx.x >> 6);
    if (node >= NN) return;
    int lane = threadIdx.x & 63;
    const float4 hv = *(const float4*)(h + (size_t)node * HID + lane * 4);
    const float4 su = *(const float4*)(sa + lane * 4);
    const float4 du = *(const float4*)(da + lane * 4);
    float ps = hv.x * su.x + hv.y * su.y + hv.z * su.z + hv.w * su.w;
    float pd = hv.x * du.x + hv.y * du.y + hv.z * du.z + hv.w * du.w;
    for (int o = 1; o < 16; o <<= 1) { ps += __shfl_xor(ps, o); pd += __shfl_xor(pd, o); }
    if ((lane & 15) == 0) {
        asrc[node * 4 + (lane >> 4)] = ps;
        adst[node * 4 + (lane >> 4)] = pd;
    }
}

// ---------------- attention scores (1 head, C=64) ----------------
__global__ void k_att1(const float* __restrict__ h,
                       const float* __restrict__ sa, const float* __restrict__ da,
                       float* __restrict__ asrc, float* __restrict__ adst) {
    int node = blockIdx.x * 4 + (threadIdx.x >> 6);
    if (node >= NN) return;
    int lane = threadIdx.x & 63;
    float hv = h[(size_t)node * OUTC + lane];
    float ps = hv * sa[lane];
    float pd = hv * da[lane];
    for (int o = 1; o < 64; o <<= 1) { ps += __shfl_xor(ps, o); pd += __shfl_xor(pd, o); }
    if (lane == 0) { asrc[node] = ps; adst[node] = pd; }
}

// ---------------- edge aggregation, 4 heads + bias + BN + ELU -> bf16 act ----------------
__global__ void k_agg4(const float* __restrict__ h,
                       const float* __restrict__ asrc, const float* __restrict__ adst,
                       const int* __restrict__ rowptr, const int* __restrict__ esrc,
                       const float* __restrict__ bias,
                       const float* __restrict__ bng, const float* __restrict__ bnb,
                       const float* __restrict__ bnm, const float* __restrict__ bnv,
                       unsigned short* __restrict__ act) {
    int node = blockIdx.x * 4 + (threadIdx.x >> 6);
    if (node >= NN) return;
    int lane = threadIdx.x & 63;
    int e0 = rowptr[node], e1 = rowptr[node + 1];
    int deg = e1 - e0;
    float4 ad = *(const float4*)(adst + (size_t)node * 4);

    float mx0 = -1e30f, mx1 = -1e30f, mx2 = -1e30f, mx3 = -1e30f;
    for (int i = lane; i < deg; i += 64) {
        int s = esrc[e0 + i];
        float4 as = *(const float4*)(asrc + (size_t)s * 4);
        mx0 = fmaxf(mx0, leaky(as.x + ad.x));
        mx1 = fmaxf(mx1, leaky(as.y + ad.y));
        mx2 = fmaxf(mx2, leaky(as.z + ad.z));
        mx3 = fmaxf(mx3, leaky(as.w + ad.w));
    }
    for (int o = 1; o < 64; o <<= 1) {
        mx0 = fmaxf(mx0, __shfl_xor(mx0, o));
        mx1 = fmaxf(mx1, __shfl_xor(mx1, o));
        mx2 = fmaxf(mx2, __shfl_xor(mx2, o));
        mx3 = fmaxf(mx3, __shfl_xor(mx3, o));
    }
    int hd = lane >> 4;
    float mh  = hd == 0 ? mx0  : hd == 1 ? mx1  : hd == 2 ? mx2  : mx3;
    float adh = hd == 0 ? ad.x : hd == 1 ? ad.y : hd == 2 ? ad.z : ad.w;

    float den = 0.f;
    float a0 = 0.f, a1 = 0.f, a2 = 0.f, a3 = 0.f;
    const size_t lc = (size_t)lane * 4;
    int i = 0;
    // 8-way unrolled: 8 independent 1KB gathers in flight per wave
    for (; i + 8 <= deg; i += 8) {
        int sv[8];
        for (int u = 0; u < 8; u++) sv[u] = esrc[e0 + i + u];
        float4 av[8], hv[8];
        for (int u = 0; u < 8; u++) av[u] = *(const float4*)(asrc + (size_t)sv[u] * 4);
        for (int u = 0; u < 8; u++) hv[u] = *(const float4*)(h + (size_t)sv[u] * HID + lc);
        for (int u = 0; u < 8; u++) {
            float e = hd == 0 ? av[u].x : hd == 1 ? av[u].y : hd == 2 ? av[u].z : av[u].w;
            float w = __expf(leaky(e + adh) - mh);
            den += w;
            a0 += w * hv[u].x; a1 += w * hv[u].y; a2 += w * hv[u].z; a3 += w * hv[u].w;
        }
    }
    for (; i + 4 <= deg; i += 4) {
        int sv[4];
        for (int u = 0; u < 4; u++) sv[u] = esrc[e0 + i + u];
        float4 av[4], hv[4];
        for (int u = 0; u < 4; u++) av[u] = *(const float4*)(asrc + (size_t)sv[u] * 4);
        for (int u = 0; u < 4; u++) hv[u] = *(const float4*)(h + (size_t)sv[u] * HID + lc);
        for (int u = 0; u < 4; u++) {
            float e = hd == 0 ? av[u].x : hd == 1 ? av[u].y : hd == 2 ? av[u].z : av[u].w;
            float w = __expf(leaky(e + adh) - mh);
            den += w;
            a0 += w * hv[u].x; a1 += w * hv[u].y; a2 += w * hv[u].z; a3 += w * hv[u].w;
        }
    }
    for (; i < deg; i++) {
        int s = esrc[e0 + i];
        float4 as = *(const float4*)(asrc + (size_t)s * 4);
        float e = hd == 0 ? as.x : hd == 1 ? as.y : hd == 2 ? as.z : as.w;
        float w = __expf(leaky(e + adh) - mh);
        den += w;
        float4 hv = *(const float4*)(h + (size_t)s * HID + lc);
        a0 += w * hv.x; a1 += w * hv.y; a2 += w * hv.z; a3 += w * hv.w;
    }
    float inv = 1.f / (den + 1e-16f);
    int c0 = lane * 4;
    float o[4] = {a0 * inv, a1 * inv, a2 * inv, a3 * inv};
    unsigned short res[4];
    for (int j = 0; j < 4; j++) {
        int c = c0 + j;
        float val = o[j] + bias[c];
        val = (val - bnm[c]) * rsqrtf(bnv[c] + BNEPS) * bng[c] + bnb[c];
        val = val > 0.f ? val : expm1f(val);
        res[j] = f2b(val);
    }
    *(ushort4*)(act + (size_t)node * HID + c0) = *(ushort4*)res;
}

// ---------------- edge aggregation, 1 head + bias -> output ----------------
__global__ void k_agg1(const float* __restrict__ h,
                       const float* __restrict__ asrc, const float* __restrict__ adst,
                       const int* __restrict__ rowptr, const int* __restrict__ esrc,
                       const float* __restrict__ bias,
                       void* __restrict__ outp, const int* __restrict__ flagB) {
    int node = blockIdx.x * 4 + (threadIdx.x >> 6);
    if (node >= NN) return;
    int lane = threadIdx.x & 63;
    int e0 = rowptr[node], e1 = rowptr[node + 1];
    int deg = e1 - e0;
    float ad = adst[node];

    float mx = -1e30f;
    for (int i = lane; i < deg; i += 64) {
        int s = esrc[e0 + i];
        mx = fmaxf(mx, leaky(asrc[s] + ad));
    }
    for (int o = 1; o < 64; o <<= 1) mx = fmaxf(mx, __shfl_xor(mx, o));

    float den = 0.f, acc = 0.f;
    int i = 0;
    for (; i + 8 <= deg; i += 8) {
        int sv[8];
        for (int u = 0; u < 8; u++) sv[u] = esrc[e0 + i + u];
        float ev[8], hv[8];
        for (int u = 0; u < 8; u++) ev[u] = asrc[sv[u]];
        for (int u = 0; u < 8; u++) hv[u] = h[(size_t)sv[u] * OUTC + lane];
        for (int u = 0; u < 8; u++) {
            float w = __expf(leaky(ev[u] + ad) - mx);
            den += w;
            acc += w * hv[u];
        }
    }
    for (; i < deg; i++) {
        int s = esrc[e0 + i];
        float w = __expf(leaky(asrc[s] + ad) - mx);
        den += w;
        acc += w * h[(size_t)s * OUTC + lane];
    }
    float val = acc / (den + 1e-16f) + bias[lane];
    if (*flagB) ((unsigned short*)outp)[(size_t)node * OUTC + lane] = f2b(val);
    else        ((float*)outp)[(size_t)node * OUTC + lane] = val;
}

// ---------------- launch ----------------
extern "C" void kernel_launch(void* const* d_in, const int* in_sizes, int n_in,
                              void* d_out, int out_size, void* d_ws, size_t ws_size,
                              hipStream_t stream) {
    const void* x  = d_in[0];
    const int*  ei = (const int*)d_in[1];
    const void* W0 = d_in[2];
    const void* W1 = d_in[10];
    const void* W2 = d_in[18];

    char* ws = (char*)d_ws;
    size_t off = 0;
    auto alloc = [&](size_t n) { void* p = ws + off; off += (n + 255) & ~(size_t)255; return p; };

    unsigned short* xb  = (unsigned short*)alloc((size_t)NN * INC * 2);
    float*          h   = (float*)alloc((size_t)NN * HID * 4);
    unsigned short* act = (unsigned short*)alloc((size_t)NN * HID * 2);
    unsigned short* WT0 = (unsigned short*)alloc((size_t)HID * INC * 2);
    unsigned short* WT1 = (unsigned short*)alloc((size_t)HID * HID * 2);
    unsigned short* WT2 = (unsigned short*)alloc((size_t)OUTC * HID * 2);
    float*          pp  = (float*)alloc((size_t)(14 * 256 + 3 * 64) * 4);
    float*  asrc   = (float*)alloc((size_t)NN * 4 * 4);
    float*  adst   = (float*)alloc((size_t)NN * 4 * 4);
    int*    cnt    = (int*)alloc((size_t)(NN + 2) * 4);
    int*    rowptr = (int*)alloc((size_t)(NN + 1) * 4);
    int*    cursor = (int*)alloc((size_t)NN * 4);
    int*    esrc   = (int*)alloc((size_t)ET * 4);
    int*    bsum   = (int*)alloc(256 * 4);
    int*    flagW  = cnt + NN;
    int*    flagB  = cnt + NN + 1;

    float* P0 = pp;                 // as0 ad0 b0 g0 be0 m0 v0 (7x256)
    float* P1 = pp + 7 * 256;       // layer1 (7x256)
    float* P2 = pp + 14 * 256;      // as2 ad2 b2 (3x64)

    const int nbN = (NN + 255) / 256;
    const int nbE = (ET + 255) / 256;
    const int nbW = (NN * 64 + 255) / 256;
    dim3 gemmGrid0((NN + 127) / 128, HID / 64);
    dim3 gemmGrid2((NN + 127) / 128, OUTC / 64);

    // dtype detection + CSR build
    k_zero<<<nbN + 1, 256, 0, stream>>>(cnt, NN + 2);
    k_detect_w<<<256, 256, 0, stream>>>(ei, flagW);
    k_detect_f<<<1, 256, 0, stream>>>((const unsigned*)x, flagB);
    k_hist<<<nbE, 256, 0, stream>>>(ei, flagW, cnt);
    k_scan_a<<<nbN, 256, 0, stream>>>(cnt, rowptr, bsum);
    k_scan_b<<<1, 256, 0, stream>>>(bsum, nbN);
    k_scan_c<<<nbN, 256, 0, stream>>>(rowptr, bsum, cursor);
    k_scatter<<<nbE, 256, 0, stream>>>(ei, flagW, cursor, esrc);

    // fused prep
    k_params<<<15, 256, 0, stream>>>(d_in[3], d_in[4], d_in[5], d_in[6], d_in[7], d_in[8], d_in[9],
                                     d_in[11], d_in[12], d_in[13], d_in[14], d_in[15], d_in[16], d_in[17],
                                     d_in[19], d_in[20], d_in[21], pp, flagB);
    k_cvt_b<<<(NN * INC + 255) / 256, 256, 0, stream>>>(x, xb, NN * INC, flagB);
    k_transp_b<<<(INC * HID + 255) / 256, 256, 0, stream>>>(W0, WT0, INC, HID, flagB);
    k_transp_b<<<(HID * HID + 255) / 256, 256, 0, stream>>>(W1, WT1, HID, HID, flagB);
    k_transp_b<<<(HID * OUTC + 255) / 256, 256, 0, stream>>>(W2, WT2, HID, OUTC, flagB);

    // ---- Layer 0 ----
    k_gemm<<<gemmGrid0, 256, 0, stream>>>(xb, WT0, h, NN, INC, HID);
    k_att4<<<nbW, 256, 0, stream>>>(h, P0 + 0, P0 + 256, asrc, adst);
    k_agg4<<<nbW, 256, 0, stream>>>(h, asrc, adst, rowptr, esrc,
                                    P0 + 512, P0 + 768, P0 + 1024, P0 + 1280, P0 + 1536, act);

    // ---- Layer 1 ----
    k_gemm<<<gemmGrid0, 256, 0, stream>>>(act, WT1, h, NN, HID, HID);
    k_att4<<<nbW, 256, 0, stream>>>(h, P1 + 0, P1 + 256, asrc, adst);
    k_agg4<<<nbW, 256, 0, stream>>>(h, asrc, adst, rowptr, esrc,
                                    P1 + 512, P1 + 768, P1 + 1024, P1 + 1280, P1 + 1536, act);

    // ---- Layer 2 ----
    k_gemm<<<gemmGrid2, 256, 0, stream>>>(act, WT2, h, NN, HID, OUTC);
    k_att1<<<nbW, 256, 0, stream>>>(h, P2 + 0, P2 + 64, asrc, adst);
    k_agg1<<<nbW, 256, 0, stream>>>(h, asrc, adst, rowptr, esrc, P2 + 128, d_out, flagB);
}

// Round 7
// 582.954 us; speedup vs baseline: 1.8161x; 1.1262x over previous
//
#include <hip/hip_runtime.h>

#define NN   50000
#define EE   800000
#define ET   850000          // EE + NN self loops
#define INC  128
#define HID  256
#define OUTC 64
#define NEG  0.2f
#define BNEPS 1e-5f

typedef __bf16 bf16x8 __attribute__((ext_vector_type(8)));
typedef float  f32x4  __attribute__((ext_vector_type(4)));

static __device__ __forceinline__ float b2f(unsigned short u) {
    return __uint_as_float(((unsigned)u) << 16);
}
static __device__ __forceinline__ unsigned short f2b(float f) {
    unsigned u = __float_as_uint(f);
    unsigned r = u + 0x7FFFu + ((u >> 16) & 1u);
    return (unsigned short)(r >> 16);
}
static __device__ __forceinline__ float leaky(float x) {
    return x > 0.f ? x : NEG * x;
}

// ---------------- dtype detection ----------------
__global__ void k_detect_w(const int* __restrict__ ei, int* __restrict__ flagW) {
    int i = blockIdx.x * 256 + threadIdx.x;
    if (i < 65536 && ei[2 * i + 1] != 0) atomicOr(flagW, 1);
}

__global__ void k_detect_f(const unsigned* __restrict__ xw, int* __restrict__ flagB) {
    __shared__ int cs[4];
    int t = threadIdx.x;
    int c = 0;
    for (int i = t; i < 4096; i += 256) {
        unsigned v = (xw[i] >> 8) & 0x7F;
        if (v >= 50 && v <= 67) c++;
    }
    for (int o = 1; o < 64; o <<= 1) c += __shfl_xor(c, o);
    if ((t & 63) == 0) cs[t >> 6] = c;
    __syncthreads();
    if (t == 0) flagB[0] = (cs[0] + cs[1] + cs[2] + cs[3] > 2048) ? 1 : 0;
}

// float input -> canonical bf16 (GEMM A operand)
__global__ void k_cvt_b(const void* __restrict__ src, unsigned short* __restrict__ dst, int n,
                        const int* __restrict__ flagB) {
    int i = blockIdx.x * 256 + threadIdx.x;
    if (i >= n) return;
    if (*flagB) dst[i] = ((const unsigned short*)src)[i];
    else        dst[i] = f2b(((const float*)src)[i]);
}

// W[K,NC] (either storage) -> WT[NC,K] bf16
__global__ void k_transp_b(const void* __restrict__ W, unsigned short* __restrict__ WT,
                           int K, int NC, const int* __restrict__ flagB) {
    int i = blockIdx.x * 256 + threadIdx.x;
    if (i >= K * NC) return;
    int k = i / NC, n = i - k * NC;
    unsigned short v = *flagB ? ((const unsigned short*)W)[i] : f2b(((const float*)W)[i]);
    WT[n * K + k] = v;
}

// All 17 small param arrays -> fp32 pp buffer in ONE launch.
__global__ void k_params(const void* p0, const void* p1, const void* p2, const void* p3,
                         const void* p4, const void* p5, const void* p6, const void* p7,
                         const void* p8, const void* p9, const void* p10, const void* p11,
                         const void* p12, const void* p13, const void* p14, const void* p15,
                         const void* p16,
                         float* __restrict__ pp, const int* __restrict__ flagB) {
    const void* srcs[17] = {p0,p1,p2,p3,p4,p5,p6,p7,p8,p9,p10,p11,p12,p13,p14,p15,p16};
    int b = blockIdx.x;
    int t = threadIdx.x;
    bool bf = (*flagB != 0);
    if (b < 14) {
        const void* s = srcs[b];
        float v = bf ? b2f(((const unsigned short*)s)[t]) : ((const float*)s)[t];
        pp[b * 256 + t] = v;
    } else if (t < 192) {
        int arr = t >> 6, j = t & 63;
        const void* s = srcs[14 + arr];
        float v = bf ? b2f(((const unsigned short*)s)[j]) : ((const float*)s)[j];
        pp[14 * 256 + arr * 64 + j] = v;
    }
}

// ---------------- CSR build ----------------
__global__ void k_zero(int* p, int n) {
    int i = blockIdx.x * 256 + threadIdx.x;
    if (i < n) p[i] = 0;
}

__global__ void k_hist(const int* __restrict__ ei, const int* __restrict__ flagW,
                       int* __restrict__ cnt) {
    int i = blockIdx.x * 256 + threadIdx.x;
    if (i >= ET) return;
    bool w32 = (*flagW != 0);
    int d = (i < EE) ? (w32 ? ei[EE + i] : ei[2 * (EE + i)]) : (i - EE);
    atomicAdd(&cnt[d], 1);
}

static __device__ __forceinline__ int block_scan_incl(int v, int t, int* ws) {
    int lane = t & 63, w = t >> 6;
    int x = v;
    for (int o = 1; o < 64; o <<= 1) {
        int y = __shfl_up(x, o);
        if (lane >= o) x += y;
    }
    if (lane == 63) ws[w] = x;
    __syncthreads();
    if (t == 0) {
        int s = 0;
        for (int k = 0; k < 4; k++) { int tmp = ws[k]; ws[k] = s; s += tmp; }
    }
    __syncthreads();
    return x + ws[w];
}

__global__ void k_scan_a(const int* __restrict__ cnt, int* __restrict__ rowptr, int* __restrict__ bsum) {
    __shared__ int ws[4];
    int t = threadIdx.x, b = blockIdx.x;
    int i = b * 256 + t;
    int v = (i < NN) ? cnt[i] : 0;
    int incl = block_scan_incl(v, t, ws);
    if (i < NN) rowptr[i] = incl - v;
    if (t == 255) bsum[b] = incl;
}

__global__ void k_scan_b(int* __restrict__ bsum, int nb) {
    __shared__ int ws[4];
    int t = threadIdx.x;
    int v = (t < nb) ? bsum[t] : 0;
    int incl = block_scan_incl(v, t, ws);
    if (t < nb) bsum[t] = incl - v;
}

__global__ void k_scan_c(int* __restrict__ rowptr, const int* __restrict__ bsum, int* __restrict__ cursor) {
    int t = threadIdx.x, b = blockIdx.x;
    int i = b * 256 + t;
    if (i < NN) {
        int r = rowptr[i] + bsum[b];
        rowptr[i] = r;
        cursor[i] = r;
    }
    if (i == 0) rowptr[NN] = ET;
}

__global__ void k_scatter(const int* __restrict__ ei, const int* __restrict__ flagW,
                          int* __restrict__ cursor, int* __restrict__ esrc) {
    int i = blockIdx.x * 256 + threadIdx.x;
    if (i >= ET) return;
    bool w32 = (*flagW != 0);
    int s, d;
    if (i < EE) {
        if (w32) { s = ei[i];     d = ei[EE + i]; }
        else     { s = ei[2 * i]; d = ei[2 * (EE + i)]; }
    } else {
        s = d = i - EE;
    }
    int p = atomicAdd(&cursor[d], 1);
    esrc[p] = s;
}

// ---------------- MFMA GEMM + fused attention scores ----------------
// H[M,NC](bf16) = A[M,K](bf16) @ W (via WT[NC,K] bf16); per bn-block = one head:
// asrc/adst[row*NH+bn] = sum_c H[row,bn*64+c] * as/ad[bn*64+c]  (exact, block-local)
template<int NC, int NH>
__global__ __launch_bounds__(256) void k_gemm(const unsigned short* __restrict__ A,
                                              const unsigned short* __restrict__ WT,
                                              unsigned short* __restrict__ H,
                                              float* __restrict__ asrc, float* __restrict__ adst,
                                              const float* __restrict__ asv, const float* __restrict__ adv,
                                              int M, int K) {
    __shared__ __align__(16) unsigned short As[128 * 40];
    __shared__ __align__(16) unsigned short Bs[64 * 40];
    int t = threadIdx.x;
    int bm = blockIdx.x, bn = blockIdx.y;
    int lane = t & 63, wave = t >> 6;
    int m16 = lane & 15, quad = lane >> 4;

    f32x4 acc[2][4];
    for (int a = 0; a < 2; a++) for (int b = 0; b < 4; b++) acc[a][b] = (f32x4){0.f, 0.f, 0.f, 0.f};

    int arow = t >> 1, ahalf = t & 1;
    int brow = t >> 2, bq = t & 3;
    long gArow = (long)bm * 128 + arow;

    for (int k0 = 0; k0 < K; k0 += 32) {
        uint4 av0 = {0u, 0u, 0u, 0u}, av1 = {0u, 0u, 0u, 0u};
        if (gArow < M) {
            const unsigned short* ap = A + gArow * (size_t)K + k0 + ahalf * 16;
            av0 = *(const uint4*)(ap);
            av1 = *(const uint4*)(ap + 8);
        }
        uint4 bv = *(const uint4*)(WT + ((size_t)bn * 64 + brow) * K + k0 + bq * 8);
        *(uint4*)&As[arow * 40 + ahalf * 16]     = av0;
        *(uint4*)&As[arow * 40 + ahalf * 16 + 8] = av1;
        *(uint4*)&Bs[brow * 40 + bq * 8]         = bv;
        __syncthreads();
        int wrow = wave * 32;
        bf16x8 af[2], bf[4];
        for (int mt = 0; mt < 2; mt++)
            af[mt] = *(const bf16x8*)&As[(wrow + mt * 16 + m16) * 40 + quad * 8];
        for (int nt = 0; nt < 4; nt++)
            bf[nt] = *(const bf16x8*)&Bs[(nt * 16 + m16) * 40 + quad * 8];
        for (int mt = 0; mt < 2; mt++)
            for (int nt = 0; nt < 4; nt++)
                acc[mt][nt] = __builtin_amdgcn_mfma_f32_16x16x32_bf16(af[mt], bf[nt], acc[mt][nt], 0, 0, 0);
        __syncthreads();
    }

    float asc[4], adc[4];
    for (int nt = 0; nt < 4; nt++) {
        int col = bn * 64 + nt * 16 + m16;
        asc[nt] = asv[col];
        adc[nt] = adv[col];
    }
    // C/D layout: col = lane&15 (m16), row = quad*4 + reg
    for (int mt = 0; mt < 2; mt++) {
        int gR0 = bm * 128 + wave * 32 + mt * 16 + quad * 4;
        for (int r = 0; r < 4; r++) {
            int gR = gR0 + r;
            float ps = 0.f, pd = 0.f;
            for (int nt = 0; nt < 4; nt++) {
                float v = acc[mt][nt][r];
                ps += v * asc[nt];
                pd += v * adc[nt];
            }
            for (int o = 1; o < 16; o <<= 1) { ps += __shfl_xor(ps, o); pd += __shfl_xor(pd, o); }
            if (m16 == 0 && gR < M) {
                asrc[(size_t)gR * NH + bn] = ps;
                adst[(size_t)gR * NH + bn] = pd;
            }
            if (gR < M) {
                for (int nt = 0; nt < 4; nt++) {
                    int gC = bn * 64 + nt * 16 + m16;
                    H[(size_t)gR * NC + gC] = f2b(acc[mt][nt][r]);
                }
            }
        }
    }
}

// ---------------- edge aggregation, 4 heads + bias + BN + ELU -> bf16 act ----------------
__global__ void k_agg4(const unsigned short* __restrict__ h,
                       const float* __restrict__ asrc, const float* __restrict__ adst,
                       const int* __restrict__ rowptr, const int* __restrict__ esrc,
                       const float* __restrict__ bias,
                       const float* __restrict__ bng, const float* __restrict__ bnb,
                       const float* __restrict__ bnm, const float* __restrict__ bnv,
                       unsigned short* __restrict__ act) {
    int node = blockIdx.x * 4 + (threadIdx.x >> 6);
    if (node >= NN) return;
    int lane = threadIdx.x & 63;
    int e0 = rowptr[node], e1 = rowptr[node + 1];
    int deg = e1 - e0;
    float4 ad = *(const float4*)(adst + (size_t)node * 4);

    float mx0 = -1e30f, mx1 = -1e30f, mx2 = -1e30f, mx3 = -1e30f;
    for (int i = lane; i < deg; i += 64) {
        int s = esrc[e0 + i];
        float4 as = *(const float4*)(asrc + (size_t)s * 4);
        mx0 = fmaxf(mx0, leaky(as.x + ad.x));
        mx1 = fmaxf(mx1, leaky(as.y + ad.y));
        mx2 = fmaxf(mx2, leaky(as.z + ad.z));
        mx3 = fmaxf(mx3, leaky(as.w + ad.w));
    }
    for (int o = 1; o < 64; o <<= 1) {
        mx0 = fmaxf(mx0, __shfl_xor(mx0, o));
        mx1 = fmaxf(mx1, __shfl_xor(mx1, o));
        mx2 = fmaxf(mx2, __shfl_xor(mx2, o));
        mx3 = fmaxf(mx3, __shfl_xor(mx3, o));
    }
    int hd = lane >> 4;
    float mh  = hd == 0 ? mx0  : hd == 1 ? mx1  : hd == 2 ? mx2  : mx3;
    float adh = hd == 0 ? ad.x : hd == 1 ? ad.y : hd == 2 ? ad.z : ad.w;

    float den = 0.f;
    float a0 = 0.f, a1 = 0.f, a2 = 0.f, a3 = 0.f;
    const size_t lc = (size_t)lane * 4;
    int i = 0;
    // 4-way unroll: 4 independent 512B gathers in flight (VGPR-light; occupancy-bound kernel)
    for (; i + 4 <= deg; i += 4) {
        int sv[4];
        for (int u = 0; u < 4; u++) sv[u] = esrc[e0 + i + u];
        float4 av[4]; ushort4 hv[4];
        for (int u = 0; u < 4; u++) av[u] = *(const float4*)(asrc + (size_t)sv[u] * 4);
        for (int u = 0; u < 4; u++) hv[u] = *(const ushort4*)(h + (size_t)sv[u] * HID + lc);
        for (int u = 0; u < 4; u++) {
            float e = hd == 0 ? av[u].x : hd == 1 ? av[u].y : hd == 2 ? av[u].z : av[u].w;
            float w = __expf(leaky(e + adh) - mh);
            den += w;
            a0 += w * b2f(hv[u].x); a1 += w * b2f(hv[u].y);
            a2 += w * b2f(hv[u].z); a3 += w * b2f(hv[u].w);
        }
    }
    for (; i < deg; i++) {
        int s = esrc[e0 + i];
        float4 as = *(const float4*)(asrc + (size_t)s * 4);
        float e = hd == 0 ? as.x : hd == 1 ? as.y : hd == 2 ? as.z : as.w;
        float w = __expf(leaky(e + adh) - mh);
        den += w;
        ushort4 hv = *(const ushort4*)(h + (size_t)s * HID + lc);
        a0 += w * b2f(hv.x); a1 += w * b2f(hv.y); a2 += w * b2f(hv.z); a3 += w * b2f(hv.w);
    }
    float inv = 1.f / (den + 1e-16f);
    int c0 = lane * 4;
    float o[4] = {a0 * inv, a1 * inv, a2 * inv, a3 * inv};
    unsigned short res[4];
    for (int j = 0; j < 4; j++) {
        int c = c0 + j;
        float val = o[j] + bias[c];
        val = (val - bnm[c]) * rsqrtf(bnv[c] + BNEPS) * bng[c] + bnb[c];
        val = val > 0.f ? val : expm1f(val);
        res[j] = f2b(val);
    }
    *(ushort4*)(act + (size_t)node * HID + c0) = *(ushort4*)res;
}

// ---------------- edge aggregation, 1 head + bias -> output ----------------
__global__ void k_agg1(const unsigned short* __restrict__ h,
                       const float* __restrict__ asrc, const float* __restrict__ adst,
                       const int* __restrict__ rowptr, const int* __restrict__ esrc,
                       const float* __restrict__ bias,
                       void* __restrict__ outp, const int* __restrict__ flagB) {
    int node = blockIdx.x * 4 + (threadIdx.x >> 6);
    if (node >= NN) return;
    int lane = threadIdx.x & 63;
    int e0 = rowptr[node], e1 = rowptr[node + 1];
    int deg = e1 - e0;
    float ad = adst[node];

    float mx = -1e30f;
    for (int i = lane; i < deg; i += 64) {
        int s = esrc[e0 + i];
        mx = fmaxf(mx, leaky(asrc[s] + ad));
    }
    for (int o = 1; o < 64; o <<= 1) mx = fmaxf(mx, __shfl_xor(mx, o));

    float den = 0.f, acc = 0.f;
    int i = 0;
    for (; i + 4 <= deg; i += 4) {
        int sv[4];
        for (int u = 0; u < 4; u++) sv[u] = esrc[e0 + i + u];
        float ev[4]; unsigned short hv[4];
        for (int u = 0; u < 4; u++) ev[u] = asrc[sv[u]];
        for (int u = 0; u < 4; u++) hv[u] = h[(size_t)sv[u] * OUTC + lane];
        for (int u = 0; u < 4; u++) {
            float w = __expf(leaky(ev[u] + ad) - mx);
            den += w;
            acc += w * b2f(hv[u]);
        }
    }
    for (; i < deg; i++) {
        int s = esrc[e0 + i];
        float w = __expf(leaky(asrc[s] + ad) - mx);
        den += w;
        acc += w * b2f(h[(size_t)s * OUTC + lane]);
    }
    float val = acc / (den + 1e-16f) + bias[lane];
    if (*flagB) ((unsigned short*)outp)[(size_t)node * OUTC + lane] = f2b(val);
    else        ((float*)outp)[(size_t)node * OUTC + lane] = val;
}

// ---------------- launch ----------------
extern "C" void kernel_launch(void* const* d_in, const int* in_sizes, int n_in,
                              void* d_out, int out_size, void* d_ws, size_t ws_size,
                              hipStream_t stream) {
    const void* x  = d_in[0];
    const int*  ei = (const int*)d_in[1];
    const void* W0 = d_in[2];
    const void* W1 = d_in[10];
    const void* W2 = d_in[18];

    char* ws = (char*)d_ws;
    size_t off = 0;
    auto alloc = [&](size_t n) { void* p = ws + off; off += (n + 255) & ~(size_t)255; return p; };

    unsigned short* xb  = (unsigned short*)alloc((size_t)NN * INC * 2);
    unsigned short* h   = (unsigned short*)alloc((size_t)NN * HID * 2);   // bf16 h (25.6 MB)
    unsigned short* act = (unsigned short*)alloc((size_t)NN * HID * 2);
    unsigned short* WT0 = (unsigned short*)alloc((size_t)HID * INC * 2);
    unsigned short* WT1 = (unsigned short*)alloc((size_t)HID * HID * 2);
    unsigned short* WT2 = (unsigned short*)alloc((size_t)OUTC * HID * 2);
    float*          pp  = (float*)alloc((size_t)(14 * 256 + 3 * 64) * 4);
    float*  asrc   = (float*)alloc((size_t)NN * 4 * 4);
    float*  adst   = (float*)alloc((size_t)NN * 4 * 4);
    int*    cnt    = (int*)alloc((size_t)(NN + 2) * 4);
    int*    rowptr = (int*)alloc((size_t)(NN + 1) * 4);
    int*    cursor = (int*)alloc((size_t)NN * 4);
    int*    esrc   = (int*)alloc((size_t)ET * 4);
    int*    bsum   = (int*)alloc(256 * 4);
    int*    flagW  = cnt + NN;
    int*    flagB  = cnt + NN + 1;

    float* P0 = pp;                 // as0 ad0 b0 g0 be0 m0 v0 (7x256)
    float* P1 = pp + 7 * 256;       // layer1
    float* P2 = pp + 14 * 256;      // as2 ad2 b2 (3x64)

    const int nbN = (NN + 255) / 256;
    const int nbE = (ET + 255) / 256;
    const int nbW = (NN * 64 + 255) / 256;
    dim3 gemmGrid0((NN + 127) / 128, HID / 64);
    dim3 gemmGrid2((NN + 127) / 128, 1);

    // dtype detection + CSR build
    k_zero<<<nbN + 1, 256, 0, stream>>>(cnt, NN + 2);
    k_detect_w<<<256, 256, 0, stream>>>(ei, flagW);
    k_detect_f<<<1, 256, 0, stream>>>((const unsigned*)x, flagB);
    k_hist<<<nbE, 256, 0, stream>>>(ei, flagW, cnt);
    k_scan_a<<<nbN, 256, 0, stream>>>(cnt, rowptr, bsum);
    k_scan_b<<<1, 256, 0, stream>>>(bsum, nbN);
    k_scan_c<<<nbN, 256, 0, stream>>>(rowptr, bsum, cursor);
    k_scatter<<<nbE, 256, 0, stream>>>(ei, flagW, cursor, esrc);

    // fused prep
    k_params<<<15, 256, 0, stream>>>(d_in[3], d_in[4], d_in[5], d_in[6], d_in[7], d_in[8], d_in[9],
                                     d_in[11], d_in[12], d_in[13], d_in[14], d_in[15], d_in[16], d_in[17],
                                     d_in[19], d_in[20], d_in[21], pp, flagB);
    k_cvt_b<<<(NN * INC + 255) / 256, 256, 0, stream>>>(x, xb, NN * INC, flagB);
    k_transp_b<<<(INC * HID + 255) / 256, 256, 0, stream>>>(W0, WT0, INC, HID, flagB);
    k_transp_b<<<(HID * HID + 255) / 256, 256, 0, stream>>>(W1, WT1, HID, HID, flagB);
    k_transp_b<<<(HID * OUTC + 255) / 256, 256, 0, stream>>>(W2, WT2, HID, OUTC, flagB);

    // ---- Layer 0 ----
    k_gemm<HID, 4><<<gemmGrid0, 256, 0, stream>>>(xb, WT0, h, asrc, adst, P0 + 0, P0 + 256, NN, INC);
    k_agg4<<<nbW, 256, 0, stream>>>(h, asrc, adst, rowptr, esrc,
                                    P0 + 512, P0 + 768, P0 + 1024, P0 + 1280, P0 + 1536, act);

    // ---- Layer 1 ----
    k_gemm<HID, 4><<<gemmGrid0, 256, 0, stream>>>(act, WT1, h, asrc, adst, P1 + 0, P1 + 256, NN, HID);
    k_agg4<<<nbW, 256, 0, stream>>>(h, asrc, adst, rowptr, esrc,
                                    P1 + 512, P1 + 768, P1 + 1024, P1 + 1280, P1 + 1536, act);

    // ---- Layer 2 (heads=1, mean==identity) ----
    k_gemm<OUTC, 1><<<gemmGrid2, 256, 0, stream>>>(act, WT2, h, asrc, adst, P2 + 0, P2 + 64, NN, HID);
    k_agg1<<<nbW, 256, 0, stream>>>(h, asrc, adst, rowptr, esrc, P2 + 128, d_out, flagB);
}